// Round 5
// baseline (155.870 us; speedup 1.0000x reference)
//
#include <hip/hip_runtime.h>
#include <math.h>

// SoftVoxelOccupancyVFE: per-voxel masked mean/var of xyz + tiny MLP + sigmoid.
// N=200000 voxels, M=32 points, C=4 channels interleaved. Memory-bound
// (~103 MB fetch floor ~= 16 us @ ~6.5 TB/s achievable).
// Layout: 4 lanes per group, 2 adjacent voxels per group -> 16 independent
// non-temporal float4 loads in flight per thread (2x MLP vs 1 voxel/group).
// One-pass variance via E[x^2]-mean^2 -> single 2-level shuffle reduction per
// voxel. num_points read once per group as int2; lane 0 stores both outputs
// as one float2.

typedef float floatx4 __attribute__((ext_vector_type(4)));

#define GROUPS_PER_BLOCK 64   // 256 threads / 4 lanes-per-group; 128 vox/block

__global__ __launch_bounds__(256) void vfe_kernel(
    const floatx4* __restrict__ feats,     // N*32 float4 (x,y,z,w)
    const int*    __restrict__ num_points, // N
    const float*  __restrict__ W1,         // 5x16 row-major
    const float*  __restrict__ b1,         // 16
    const float*  __restrict__ W2,         // 16x1
    const float*  __restrict__ b2,         // 1
    float*        __restrict__ out,        // N
    int Npairs)                            // N/2
{
    __shared__ float sW1[80];
    __shared__ float sb1[16];
    __shared__ float sW2[16];
    __shared__ float sb2;

    const int t = threadIdx.x;
    if (t < 80) sW1[t] = W1[t];
    if (t < 16) { sb1[t] = b1[t]; sW2[t] = W2[t]; }
    if (t == 0) sb2 = b2[0];
    __syncthreads();

    const int j    = t & 3;                // lane within group (0..3)
    const int pair = blockIdx.x * GROUPS_PER_BLOCK + (t >> 2);
    if (pair >= Npairs) return;

    // both voxels' point counts in one 8 B load (broadcast within group)
    const int2 np2  = ((const int2*)num_points)[pair];
    const float npf0 = (float)np2.x;
    const float npf1 = (float)np2.y;
    const float inv_d0 = 1.0f / fmaxf(npf0, 1.0f);
    const float inv_d1 = 1.0f / fmaxf(npf1, 1.0f);

    // 16 independent non-temporal 16 B loads per thread
    const floatx4* vb0 = feats + (size_t)pair * 64;
    const floatx4* vb1 = vb0 + 32;
    floatx4 f0[8], f1[8];
    #pragma unroll
    for (int i = 0; i < 8; ++i) f0[i] = __builtin_nontemporal_load(&vb0[j + 4 * i]);
    #pragma unroll
    for (int i = 0; i < 8; ++i) f1[i] = __builtin_nontemporal_load(&vb1[j + 4 * i]);

    // local masked partials for both voxels
    float sx0 = 0.f, sy0 = 0.f, sz0 = 0.f, sq0 = 0.f;
    float sx1 = 0.f, sy1 = 0.f, sz1 = 0.f, sq1 = 0.f;
    #pragma unroll
    for (int i = 0; i < 8; ++i) {
        const int   p  = j + 4 * i;
        const float m0 = (p < np2.x) ? 1.0f : 0.0f;
        const float m1 = (p < np2.y) ? 1.0f : 0.0f;
        sx0 += f0[i].x * m0;  sy0 += f0[i].y * m0;  sz0 += f0[i].z * m0;
        sq0 += m0 * (f0[i].x * f0[i].x + f0[i].y * f0[i].y + f0[i].z * f0[i].z);
        sx1 += f1[i].x * m1;  sy1 += f1[i].y * m1;  sz1 += f1[i].z * m1;
        sq1 += m1 * (f1[i].x * f1[i].x + f1[i].y * f1[i].y + f1[i].z * f1[i].z);
    }

    // 2-level butterfly over the 4-lane group (xor masks stay in-group)
    #pragma unroll
    for (int d = 1; d <= 2; d <<= 1) {
        sx0 += __shfl_xor(sx0, d);  sy0 += __shfl_xor(sy0, d);
        sz0 += __shfl_xor(sz0, d);  sq0 += __shfl_xor(sq0, d);
        sx1 += __shfl_xor(sx1, d);  sy1 += __shfl_xor(sy1, d);
        sz1 += __shfl_xor(sz1, d);  sq1 += __shfl_xor(sq1, d);
    }

    const float mx0 = sx0 * inv_d0, my0 = sy0 * inv_d0, mz0 = sz0 * inv_d0;
    const float mx1 = sx1 * inv_d1, my1 = sy1 * inv_d1, mz1 = sz1 * inv_d1;

    // sum of masked squared deviations = sq - (sx^2+sy^2+sz^2)/denom
    const float q0 = fmaxf(sq0 - (sx0*sx0 + sy0*sy0 + sz0*sz0) * inv_d0, 0.0f);
    const float q1 = fmaxf(sq1 - (sx1*sx1 + sy1*sy1 + sz1*sz1) * inv_d1, 0.0f);
    const float pv0 = __expf(-0.5f * q0 * inv_d0 * (1.0f / 3.0f));
    const float pv1 = __expf(-0.5f * q1 * inv_d1 * (1.0f / 3.0f));
    const float pd0 = fminf(npf0, 10.0f) * 0.1f;
    const float pd1 = fminf(npf1, 10.0f) * 0.1f;

    // MLP: lane j computes hidden units j, j+4, j+8, j+12 for both voxels
    float c0 = 0.0f, c1 = 0.0f;
    #pragma unroll
    for (int u0 = 0; u0 < 16; u0 += 4) {
        const int u = u0 + j;
        const float w_pd = sW1[u],       w_pv = sW1[16 + u];
        const float w_mx = sW1[32 + u],  w_my = sW1[48 + u], w_mz = sW1[64 + u];
        const float bias = sb1[u],       w2   = sW2[u];
        float h0 = bias + pd0*w_pd + pv0*w_pv + mx0*w_mx + my0*w_my + mz0*w_mz;
        float h1 = bias + pd1*w_pd + pv1*w_pv + mx1*w_mx + my1*w_my + mz1*w_mz;
        c0 += fmaxf(h0, 0.0f) * w2;
        c1 += fmaxf(h1, 0.0f) * w2;
    }
    c0 += __shfl_xor(c0, 1);  c0 += __shfl_xor(c0, 2);
    c1 += __shfl_xor(c1, 1);  c1 += __shfl_xor(c1, 2);

    if (j == 0) {
        float2 r;
        r.x = 1.0f / (1.0f + __expf(-(c0 + sb2)));
        r.y = 1.0f / (1.0f + __expf(-(c1 + sb2)));
        ((float2*)out)[pair] = r;
    }
}

extern "C" void kernel_launch(void* const* d_in, const int* in_sizes, int n_in,
                              void* d_out, int out_size, void* d_ws, size_t ws_size,
                              hipStream_t stream) {
    // setup_inputs order: features, num_points, coors, W1, b1, W2, b2
    const floatx4* feats     = (const floatx4*)d_in[0];
    const int*    num_points = (const int*)d_in[1];
    // d_in[2] = coors (unused by the reference)
    const float*  W1 = (const float*)d_in[3];
    const float*  b1 = (const float*)d_in[4];
    const float*  W2 = (const float*)d_in[5];
    const float*  b2 = (const float*)d_in[6];
    float* out = (float*)d_out;

    const int N      = in_sizes[1];            // 200000 (even)
    const int Npairs = N / 2;
    const int blocks = (Npairs + GROUPS_PER_BLOCK - 1) / GROUPS_PER_BLOCK;
    vfe_kernel<<<blocks, 256, 0, stream>>>(feats, num_points, W1, b1, W2, b2, out, Npairs);
}

// Round 6
// 153.895 us; speedup vs baseline: 1.0128x; 1.0128x over previous
//
#include <hip/hip_runtime.h>
#include <math.h>

// SoftVoxelOccupancyVFE: per-voxel masked mean/var of xyz + tiny MLP + sigmoid.
// N=200000 voxels, M=32 points, C=4 channels interleaved. Memory-bound
// (~103 MB fetch floor ~= 16.5 us @ ~6.3 TB/s achievable).
// Layout (best measured, round 4): 4 lanes per voxel, each lane loads 8 points
// (8 independent nt float4 loads), one-pass variance via E[x^2]-mean^2 ->
// single 2-level shuffle reduction. __launch_bounds__(256,8) pins VGPR <= 64
// for 8 waves/SIMD — round 5 showed the kernel is occupancy/latency-sensitive
// (2-voxel/group variant with ~2x live registers regressed +5 us).

typedef float floatx4 __attribute__((ext_vector_type(4)));

#define LANES_PER_VOX 4
#define VOX_PER_BLOCK 64   // 256 threads / 4 lanes-per-voxel

__global__ __launch_bounds__(256, 8) void vfe_kernel(
    const floatx4* __restrict__ feats,     // N*32 float4 (x,y,z,w)
    const int*    __restrict__ num_points, // N
    const float*  __restrict__ W1,         // 5x16 row-major
    const float*  __restrict__ b1,         // 16
    const float*  __restrict__ W2,         // 16x1
    const float*  __restrict__ b2,         // 1
    float*        __restrict__ out,        // N
    int N)
{
    __shared__ float sW1[80];
    __shared__ float sb1[16];
    __shared__ float sW2[16];
    __shared__ float sb2;

    const int t = threadIdx.x;
    if (t < 80) sW1[t] = W1[t];
    if (t < 16) { sb1[t] = b1[t]; sW2[t] = W2[t]; }
    if (t == 0) sb2 = b2[0];
    __syncthreads();

    const int j   = t & 3;                 // lane within voxel group (0..3)
    const int vox = blockIdx.x * VOX_PER_BLOCK + (t >> 2);
    if (vox >= N) return;

    const int   np        = num_points[vox];
    const float npf       = (float)np;
    const float inv_denom = 1.0f / fmaxf(npf, 1.0f);

    // 8 independent non-temporal 16 B loads per lane; group of 4 lanes covers
    // one contiguous 64 B line per load instruction.
    const floatx4* vbase = feats + (size_t)vox * 32;
    floatx4 f[8];
    #pragma unroll
    for (int i = 0; i < 8; ++i)
        f[i] = __builtin_nontemporal_load(&vbase[j + 4 * i]);

    // local masked partials
    float sx = 0.0f, sy = 0.0f, sz = 0.0f, sq = 0.0f;
    #pragma unroll
    for (int i = 0; i < 8; ++i) {
        const float m = (j + 4 * i < np) ? 1.0f : 0.0f;
        sx += f[i].x * m;
        sy += f[i].y * m;
        sz += f[i].z * m;
        sq += m * (f[i].x * f[i].x + f[i].y * f[i].y + f[i].z * f[i].z);
    }

    // single 2-level reduction over the 4-lane group (xor masks stay in-group)
    #pragma unroll
    for (int d = 1; d <= 2; d <<= 1) {
        sx += __shfl_xor(sx, d);
        sy += __shfl_xor(sy, d);
        sz += __shfl_xor(sz, d);
        sq += __shfl_xor(sq, d);
    }

    const float mean_x = sx * inv_denom;
    const float mean_y = sy * inv_denom;
    const float mean_z = sz * inv_denom;

    // sum m*(x-mx)^2 etc = sq - (sx^2+sy^2+sz^2)/denom  (exact; 0 for np=0)
    float qtot = sq - (sx * sx + sy * sy + sz * sz) * inv_denom;
    float var_mean = fmaxf(qtot, 0.0f) * inv_denom * (1.0f / 3.0f);

    const float p_var     = __expf(-0.5f * var_mean);
    const float p_density = fminf(npf, 10.0f) * 0.1f;

    // MLP: lane j computes hidden units j, j+4, j+8, j+12; 2-level reduce
    float c = 0.0f;
    #pragma unroll
    for (int u0 = 0; u0 < 16; u0 += 4) {
        const int u = u0 + j;
        float h = sb1[u]
                + p_density * sW1[u]
                + p_var     * sW1[16 + u]
                + mean_x    * sW1[32 + u]
                + mean_y    * sW1[48 + u]
                + mean_z    * sW1[64 + u];
        c += fmaxf(h, 0.0f) * sW2[u];
    }
    c += __shfl_xor(c, 1);
    c += __shfl_xor(c, 2);

    if (j == 0) {
        const float logit = c + sb2;
        out[vox] = 1.0f / (1.0f + __expf(-logit));
    }
}

extern "C" void kernel_launch(void* const* d_in, const int* in_sizes, int n_in,
                              void* d_out, int out_size, void* d_ws, size_t ws_size,
                              hipStream_t stream) {
    // setup_inputs order: features, num_points, coors, W1, b1, W2, b2
    const floatx4* feats     = (const floatx4*)d_in[0];
    const int*    num_points = (const int*)d_in[1];
    // d_in[2] = coors (unused by the reference)
    const float*  W1 = (const float*)d_in[3];
    const float*  b1 = (const float*)d_in[4];
    const float*  W2 = (const float*)d_in[5];
    const float*  b2 = (const float*)d_in[6];
    float* out = (float*)d_out;

    const int N = in_sizes[1];                 // 200000
    const int blocks = (N + VOX_PER_BLOCK - 1) / VOX_PER_BLOCK;
    vfe_kernel<<<blocks, 256, 0, stream>>>(feats, num_points, W1, b1, W2, b2, out, N);
}